// Round 7
// baseline (387.815 us; speedup 1.0000x reference)
//
#include <hip/hip_runtime.h>

typedef short v8s __attribute__((ext_vector_type(8)));
typedef float v4f __attribute__((ext_vector_type(4)));

__device__ __forceinline__ short f2bf(float f) {
  union { float f; unsigned u; } v; v.f = f;
  unsigned r = v.u + 0x7FFFu + ((v.u >> 16) & 1u);
  return (short)(r >> 16);
}

// async global->LDS, 16B per lane; LDS dst = wave-uniform base + lane*16
__device__ __forceinline__ void gll16(const short* g, short* l) {
  __builtin_amdgcn_global_load_lds(
      (const __attribute__((address_space(1))) void*)g,
      (__attribute__((address_space(3))) void*)l, 16, 0, 0);
}

// ---------------- merged: x cast (blocks 0..8191) + weight transposes ----------------
// Wq is pre-scaled by softmax_scale*log2(e) so flash computes exp2(S) with no per-
// element multiply (S^T values already include the factor).
__global__ void cast_and_transpose(const float* __restrict__ x, short* __restrict__ xb,
                                   const float* __restrict__ Wq, const float* __restrict__ Wk,
                                   const float* __restrict__ Wv, const float* __restrict__ Wo,
                                   short* __restrict__ Wqkvt, short* __restrict__ Wot) {
  const int tid = threadIdx.x;
  int bid = blockIdx.x;
  if (bid < 8192) {
    int i = bid * 256 + tid;
    float4 v = ((const float4*)x)[i];
    short4 o;
    o.x = f2bf(v.x); o.y = f2bf(v.y); o.z = f2bf(v.z); o.w = f2bf(v.w);
    ((short4*)xb)[i] = o;
    return;
  }
  __shared__ float tile[32][33];
  bid -= 8192;
  const int tx = tid & 31, ty = tid >> 5;
  int bx = bid % 160;
  const int byy = bid / 160;
  const float* src; short* dst; int C, cb; float fac = 1.0f;
  if (bx < 64)      { src = Wq; dst = Wqkvt;                        C = 2048; cb = bx;
                      fac = 0.08838834764831845f * 1.4426950408889634f; }  // scale*log2e
  else if (bx < 80) { src = Wk; dst = Wqkvt + (size_t)2048 * 2048;  C = 512;  cb = bx - 64; }
  else if (bx < 96) { src = Wv; dst = Wqkvt + (size_t)2560 * 2048;  C = 512;  cb = bx - 80; }
  else              { src = Wo; dst = Wot;                          C = 2048; cb = bx - 96; }
  const int c0 = cb * 32, r0 = byy * 32;
#pragma unroll
  for (int i = 0; i < 4; ++i)
    tile[ty + 8 * i][tx] = src[(size_t)(r0 + ty + 8 * i) * C + c0 + tx];
  __syncthreads();
#pragma unroll
  for (int i = 0; i < 4; ++i)
    dst[(size_t)(c0 + ty + 8 * i) * 2048 + r0 + tx] = f2bf(tile[tx][ty + 8 * i] * fac);
}

// ---------------- V transpose + key-permute out of packed QKV ----------------
__global__ void transpose_v_perm(const short* __restrict__ qkv, short* __restrict__ out) {
  __shared__ short tile[32][33];
  const int tx = threadIdx.x, ty = threadIdx.y;
  const int c0 = blockIdx.x * 32, r0 = blockIdx.y * 32;
  const int z = blockIdx.z;
#pragma unroll
  for (int i = 0; i < 4; ++i)
    tile[ty + 8 * i][tx] = qkv[(size_t)(z * 2048 + r0 + ty + 8 * i) * 3072 + 2560 + c0 + tx];
  __syncthreads();
#pragma unroll
  for (int i = 0; i < 4; ++i) {
    int k = r0 + tx;
    int pk = (k & ~31) | ((((k >> 2) & 3) * 2 + ((k >> 4) & 1)) * 4) | (k & 3);
    out[(size_t)z * 512 * 2048 + (size_t)(c0 + ty + 8 * i) * 2048 + pk] = tile[tx][ty + 8 * i];
  }
}

// ---------------- GEMM v3g: C[M][N] = A[M][K] @ Bt[N][K]^T (bf16 in) ----------------
// 128x128 tile, BK=32, 2-phase __syncthreads pipeline (verified skeleton). LDS-BW fix:
// B-fragments bypass LDS entirely — loaded global->VGPR (4x dwordx4/wave/K-step; the
// 4 quads of a wave read 4 contiguous 16B chunks of 16 rows = 16 fully-used 64B lines,
// paired wave L1-dedups) with 1-tile ping-pong prefetch (b0/b1, t-loop unrolled x2 for
// static reg indexing). End-of-step __syncthreads doubles as the vmcnt drain; load
// latency hides under the MFMA phase + 3-blocks/CU overlap. A stays via gll16+XOR
// swizzle (verified). LDS traffic/CU-K-step: 144->72 KiB => MFMA-bound (~563 vs 774 cyc).
template <int BF16_OUT>
__global__ __launch_bounds__(256, 3) void gemm_bt2p(const short* __restrict__ A,
                                                    const short* __restrict__ Bt,
                                                    void* __restrict__ Cout,
                                                    const float* __restrict__ bias,
                                                    int N, int K, int nbx, int cpx) {
  __shared__ __align__(16) short sm[2 * 4096];  // 2 bufs x A[128][32]
  const int tid = threadIdx.x;
  const int w = tid >> 6, lane = tid & 63, quad = lane >> 4, l16 = lane & 15;
  const int wm = (w >> 1) * 64, wn = (w & 1) * 64;
  const int bid = blockIdx.x;
  const int swz = (bid & 7) * cpx + (bid >> 3);
  const int n0 = (swz % nbx) * 128, m0 = (swz / nbx) * 128;
  const int NT = K >> 5;  // even for K=2048

  // A staging: wave w stages rows {w*16+srow, 64+w*16+srow}; XOR chunk swizzle
  const int srow = lane >> 2;
  const int sc = ((lane & 3) ^ ((lane >> 2) & 3) ^ ((lane >> 4) & 3)) * 8;
  const short* Ag = A + (size_t)(m0 + w * 16 + srow) * K + sc;
  short* Ad = sm + w * 512 + lane * 8;
  const size_t rjump = (size_t)64 * K;

  auto stageA = [&](int t, int bf_) {
    const int k = t << 5;
    short* ad = Ad + bf_ * 4096;
    gll16(Ag + k, ad);
    gll16(Ag + k + rjump, ad + 2048);
  };

  // A frag reads: row = wm + i*16 + l16; chunk quad at slot quad^(l16&3)^((l16>>2)&3)
  const int rsc = (quad ^ (l16 & 3) ^ ((l16 >> 2) & 3)) * 8;
  const short* aBase = sm + (wm + l16) * 32 + rsc;

  // B frag global base: row n0+wn+i*16+l16, chunk quad (identical data to the old
  // unswizzled LDS read — correctness preserved by construction)
  const short* Bgf = Bt + (size_t)(n0 + wn + l16) * K + quad * 8;
  auto loadB = [&](v8s* dst, int t) {
    const short* p = Bgf + (t << 5);
#pragma unroll
    for (int i = 0; i < 4; ++i) dst[i] = *(const v8s*)(p + (size_t)(i * 16) * K);
  };

  v4f acc[4][4] = {};
  v8s b0[4], b1[4];

  stageA(0, 0);
  loadB(b0, 0);
  __syncthreads();

  for (int t = 0; t < NT; t += 2) {
    // even step t: compute buf0 with b0; prefetch tile t+1 (A->buf1, B->b1)
    {
      stageA(t + 1, 1);
      loadB(b1, t + 1);
      v8s af[4];
#pragma unroll
      for (int i = 0; i < 4; ++i) af[i] = *(const v8s*)(aBase + i * 512);
      __builtin_amdgcn_s_setprio(1);
#pragma unroll
      for (int mi = 0; mi < 4; ++mi)
#pragma unroll
        for (int ni = 0; ni < 4; ++ni)
          acc[mi][ni] = __builtin_amdgcn_mfma_f32_16x16x32_bf16(af[mi], b0[ni], acc[mi][ni], 0, 0, 0);
      __builtin_amdgcn_s_setprio(0);
      __syncthreads();  // drains prefetch; publishes buf1; protects buf0 for rewrite
    }
    // odd step t+1: compute buf1 with b1; prefetch tile t+2 (A->buf0, B->b0)
    {
      if (t + 2 < NT) {
        stageA(t + 2, 0);
        loadB(b0, t + 2);
      }
      v8s af[4];
#pragma unroll
      for (int i = 0; i < 4; ++i) af[i] = *(const v8s*)(aBase + 4096 + i * 512);
      __builtin_amdgcn_s_setprio(1);
#pragma unroll
      for (int mi = 0; mi < 4; ++mi)
#pragma unroll
        for (int ni = 0; ni < 4; ++ni)
          acc[mi][ni] = __builtin_amdgcn_mfma_f32_16x16x32_bf16(af[mi], b1[ni], acc[mi][ni], 0, 0, 0);
      __builtin_amdgcn_s_setprio(0);
      if (t + 2 < NT) __syncthreads();
    }
  }

#pragma unroll
  for (int mi = 0; mi < 4; ++mi) {
#pragma unroll
    for (int ni = 0; ni < 4; ++ni) {
      const int col = n0 + wn + ni * 16 + l16;
#pragma unroll
      for (int r = 0; r < 4; ++r) {
        const int row = m0 + wm + mi * 16 + quad * 4 + r;
        if (BF16_OUT) {
          ((short*)Cout)[(size_t)row * N + col] = f2bf(acc[mi][ni][r]);
        } else {
          ((float*)Cout)[(size_t)row * N + col] = acc[mi][ni][r] + bias[col];
        }
      }
    }
  }
}

// ---------------- flash attention v7 ----------------
// (byte-identical to round-6 verified version)
__global__ __launch_bounds__(512, 4) void flash_attn7(const short* __restrict__ QKV,
                                                      const short* __restrict__ Vtb,
                                                      short* __restrict__ ctx) {
  __shared__ __align__(16) short smem[32768];  // 2 x (Ks 8192 + Vs 8192); epilogue overlay
  const int tid = threadIdx.x;
  const int w = tid >> 6, lane = tid & 63, quad = lane >> 4, l16 = lane & 15;
  const int wq = w >> 1, wk = w & 1;
  const int bh = blockIdx.y;
  const int b = bh >> 4, h = bh & 15, g = h >> 2;
  v8s ones;
#pragma unroll
  for (int i = 0; i < 8; ++i) ones[i] = (short)0x3F80;

  // staging lane roles: wave w stages K rows w*8..+7 and V d-rows w*16..+15
  const int krl = lane >> 4, kcl = lane & 15;
  const int vrl = lane >> 3, vcl = lane & 7;
  const short* Kg0 = QKV + (size_t)(b * 2048 + w * 8 + krl) * 3072 + 2048 + g * 128;
  const short* Vg0 = Vtb + (size_t)(b * 512 + g * 128 + w * 16 + vrl) * 2048 + (vcl ^ (vrl & 7)) * 8;
  short* kd = smem + (w * 8) * 128 + lane * 8;
  short* vd = smem + 8192 + (w * 16) * 64 + lane * 8;

  auto stage = [&](int key0, int bs) {
    const short* kg = Kg0 + (size_t)key0 * 3072;
    const short* vg = Vg0 + key0;
#pragma unroll
    for (int ii = 0; ii < 2; ++ii) {
      const int rl = (w & 1) * 8 + ii * 4 + krl;   // = (staged K row) & 15
      gll16(kg + (size_t)(ii * 4) * 3072 + (kcl ^ rl) * 8, kd + bs * 16384 + ii * 512);
      gll16(vg + (size_t)(ii * 8) * 2048, vd + bs * 16384 + ii * 512);
    }
  };

  float* red = (float*)smem;

#pragma unroll 1
  for (int half = 0; half < 2; ++half) {
    const int qt = half ? (31 - blockIdx.x) : blockIdx.x;
    const int q0 = qt * 64;
    const int qb = q0 + wq * 16;

    // Q fragments: this wave's 16 rows (serve as MFMA B-operand for S^T = K*Q^T)
    v8s aq[4];
    {
      const short* Qp = QKV + (size_t)(b * 2048 + qb + l16) * 3072 + h * 128 + quad * 8;
#pragma unroll
      for (int kk = 0; kk < 4; ++kk) aq[kk] = *(const v8s*)(Qp + kk * 32);
    }
    v4f o[8] = {};
    v4f ol = {};

    __syncthreads();            // protect smem from previous half's epilogue readers
    stage(0, 0);
    const int nk = qt + 1;
#pragma unroll 1
    for (int kt = 0; kt < nk; ++kt) {
      const int key0 = kt << 6;
      __syncthreads();          // drains stage(kt) [vmcnt(0)], orders buffer reuse
      if (kt + 1 < nk) stage((kt + 1) << 6, (kt + 1) & 1);
      const short* Ks = smem + (kt & 1) * 16384;
      const short* Vs = Ks + 8192;
      const int kb = key0 + wk * 32;
      if (kb > qb + 15) continue;  // wave-uniform: fully masked
      // S^T = K @ Q^T for this wave's 32 keys x 16 q (S already includes scale*log2e)
      v4f sf[2] = {};
      __builtin_amdgcn_s_setprio(1);
#pragma unroll
      for (int kfl = 0; kfl < 2; ++kfl)
#pragma unroll
        for (int kk = 0; kk < 4; ++kk) {
          v8s kfr = *(const v8s*)&Ks[((wk * 2 + kfl) * 16 + l16) * 128 + (((kk * 4 + quad) ^ l16) * 8)];
          sf[kfl] = __builtin_amdgcn_mfma_f32_16x16x32_bf16(kfr, aq[kk], sf[kfl], 0, 0, 0);
        }
      __builtin_amdgcn_s_setprio(0);
      // mask + exp2 + pack P^T C-layout -> PV A-frag (32 keys)
      const bool diag = (kb + 31 > qb);
      const int qg = qb + l16;
      union { v8s v; unsigned u[4]; } pu;
#pragma unroll
      for (int kfl = 0; kfl < 2; ++kfl) {
        float e[4];
#pragma unroll
        for (int r = 0; r < 4; ++r) {
          float s = sf[kfl][r];
          if (diag && (kb + kfl * 16 + quad * 4 + r > qg)) s = -1e30f;
          e[r] = exp2f(s);
        }
        asm("v_cvt_pk_bf16_f32 %0, %1, %2" : "=v"(pu.u[kfl * 2 + 0]) : "v"(e[0]), "v"(e[1]));
        asm("v_cvt_pk_bf16_f32 %0, %1, %2" : "=v"(pu.u[kfl * 2 + 1]) : "v"(e[2]), "v"(e[3]));
      }
      const v8s pa = pu.v;
      // O += P @ V ; l += P @ 1
      __builtin_amdgcn_s_setprio(1);
#pragma unroll
      for (int nf = 0; nf < 8; ++nf) {
        v8s vf = *(const v8s*)&Vs[(nf * 16 + l16) * 64 + (((wk * 4 + quad) ^ (l16 & 7)) * 8)];
        o[nf] = __builtin_amdgcn_mfma_f32_16x16x32_bf16(pa, vf, o[nf], 0, 0, 0);
      }
      ol = __builtin_amdgcn_mfma_f32_16x16x32_bf16(pa, ones, ol, 0, 0, 0);
      __builtin_amdgcn_s_setprio(0);
    }
    __syncthreads();   // all LDS reads of K/V done; smem becomes reduction buffer

    // ---- epilogue: sum o/l across the wk pair, normalize, store ----
    // phase A: l
    if (wk == 1)
      *(v4f*)&red[wq * 256 + l16 * 16 + quad * 4] = ol;
    __syncthreads();
    if (wk == 0)
      ol += *(const v4f*)&red[wq * 256 + l16 * 16 + quad * 4];
    __syncthreads();
    // phase B: o
    if (wk == 1) {
#pragma unroll
      for (int nf = 0; nf < 8; ++nf)
        *(v4f*)&red[(wq * 8 + nf) * 256 + l16 * 16 + quad * 4] = o[nf];
    }
    __syncthreads();
    if (wk == 0) {
      float inv[4];
#pragma unroll
      for (int r = 0; r < 4; ++r) inv[r] = 1.0f / ol[r];
#pragma unroll
      for (int nf = 0; nf < 8; ++nf) {
        v4f osum = o[nf] + *(const v4f*)&red[(wq * 8 + nf) * 256 + l16 * 16 + quad * 4];
#pragma unroll
        for (int r = 0; r < 4; ++r) {
          const int row = qb + quad * 4 + r;
          ctx[(size_t)(b * 2048 + row) * 2048 + h * 128 + nf * 16 + l16] = f2bf(osum[r] * inv[r]);
        }
      }
    }
  }
}

extern "C" void kernel_launch(void* const* d_in, const int* in_sizes, int n_in,
                              void* d_out, int out_size, void* d_ws, size_t ws_size,
                              hipStream_t stream) {
  const float* x = (const float*)d_in[0];
  const float* Wq = (const float*)d_in[1];
  const float* Wk = (const float*)d_in[2];
  const float* Wv = (const float*)d_in[3];
  const float* Wo = (const float*)d_in[4];
  const float* bo = (const float*)d_in[5];
  float* out = (float*)d_out;
  char* ws = (char*)d_ws;

  // workspace layout (bytes), total 64 MiB; ctx aliases xb
  short* xb    = (short*)(ws);             // 16,777,216  x bf16 [4096][2048]
  short* ctx   = (short*)(ws);             // alias       [4096][2048]
  short* Wqkvt = (short*)(ws + 16777216);  // 12,582,912  [3072 n][2048 k] packed Q|K|V
  short* Wot   = (short*)(ws + 29360128);  //  8,388,608  [2048 n][2048 k]
  short* QKV   = (short*)(ws + 37748736);  // 25,165,824  [4096][3072]
  short* Vtb   = (short*)(ws + 62914560);  //  4,194,304  [b][512][2048] key-permuted

  cast_and_transpose<<<18432, 256, 0, stream>>>(x, xb, Wq, Wk, Wv, Wo, Wqkvt, Wot);

  // QKV: M=4096,N=3072,K=2048 -> 24x32=768 blocks = exactly 3/CU
  gemm_bt2p<1><<<768, 256, 0, stream>>>(xb, Wqkvt, (void*)QKV, nullptr, 3072, 2048, 24, 96);

  transpose_v_perm<<<dim3(16, 64, 2), dim3(32, 8), 0, stream>>>(QKV, Vtb);

  flash_attn7<<<dim3(16, 32), 512, 0, stream>>>(QKV, Vtb, ctx);

  // out: M=4096,N=2048,K=2048 -> 16x32=512 blocks = 2/CU
  gemm_bt2p<0><<<512, 256, 0, stream>>>(ctx, Wot, (void*)out, bo, 2048, 2048, 16, 64);
}

// Round 8
// 279.512 us; speedup vs baseline: 1.3875x; 1.3875x over previous
//
#include <hip/hip_runtime.h>

typedef short v8s __attribute__((ext_vector_type(8)));
typedef float v4f __attribute__((ext_vector_type(4)));

__device__ __forceinline__ short f2bf(float f) {
  union { float f; unsigned u; } v; v.f = f;
  unsigned r = v.u + 0x7FFFu + ((v.u >> 16) & 1u);
  return (short)(r >> 16);
}

// async global->LDS, 16B per lane; LDS dst = wave-uniform base + lane*16
__device__ __forceinline__ void gll16(const short* g, short* l) {
  __builtin_amdgcn_global_load_lds(
      (const __attribute__((address_space(1))) void*)g,
      (__attribute__((address_space(3))) void*)l, 16, 0, 0);
}

// ---------------- merged: x cast (blocks 0..8191) + weight transposes ----------------
// Wq is pre-scaled by softmax_scale*log2(e) so flash computes exp2(S) directly.
__global__ void cast_and_transpose(const float* __restrict__ x, short* __restrict__ xb,
                                   const float* __restrict__ Wq, const float* __restrict__ Wk,
                                   const float* __restrict__ Wv, const float* __restrict__ Wo,
                                   short* __restrict__ Wqkvt, short* __restrict__ Wot) {
  const int tid = threadIdx.x;
  int bid = blockIdx.x;
  if (bid < 8192) {
    int i = bid * 256 + tid;
    float4 v = ((const float4*)x)[i];
    short4 o;
    o.x = f2bf(v.x); o.y = f2bf(v.y); o.z = f2bf(v.z); o.w = f2bf(v.w);
    ((short4*)xb)[i] = o;
    return;
  }
  __shared__ float tile[32][33];
  bid -= 8192;
  const int tx = tid & 31, ty = tid >> 5;
  int bx = bid % 160;
  const int byy = bid / 160;
  const float* src; short* dst; int C, cb; float fac = 1.0f;
  if (bx < 64)      { src = Wq; dst = Wqkvt;                        C = 2048; cb = bx;
                      fac = 0.08838834764831845f * 1.4426950408889634f; }  // scale*log2e
  else if (bx < 80) { src = Wk; dst = Wqkvt + (size_t)2048 * 2048;  C = 512;  cb = bx - 64; }
  else if (bx < 96) { src = Wv; dst = Wqkvt + (size_t)2560 * 2048;  C = 512;  cb = bx - 80; }
  else              { src = Wo; dst = Wot;                          C = 2048; cb = bx - 96; }
  const int c0 = cb * 32, r0 = byy * 32;
#pragma unroll
  for (int i = 0; i < 4; ++i)
    tile[ty + 8 * i][tx] = src[(size_t)(r0 + ty + 8 * i) * C + c0 + tx];
  __syncthreads();
#pragma unroll
  for (int i = 0; i < 4; ++i)
    dst[(size_t)(c0 + ty + 8 * i) * 2048 + r0 + tx] = f2bf(tile[tx][ty + 8 * i] * fac);
}

// ---------------- V transpose + key-permute out of packed QKV ----------------
__global__ void transpose_v_perm(const short* __restrict__ qkv, short* __restrict__ out) {
  __shared__ short tile[32][33];
  const int tx = threadIdx.x, ty = threadIdx.y;
  const int c0 = blockIdx.x * 32, r0 = blockIdx.y * 32;
  const int z = blockIdx.z;
#pragma unroll
  for (int i = 0; i < 4; ++i)
    tile[ty + 8 * i][tx] = qkv[(size_t)(z * 2048 + r0 + ty + 8 * i) * 3072 + 2560 + c0 + tx];
  __syncthreads();
#pragma unroll
  for (int i = 0; i < 4; ++i) {
    int k = r0 + tx;
    int pk = (k & ~31) | ((((k >> 2) & 3) * 2 + ((k >> 4) & 1)) * 4) | (k & 3);
    out[(size_t)z * 512 * 2048 + (size_t)(c0 + ty + 8 * i) * 2048 + pk] = tile[tx][ty + 8 * i];
  }
}

// ---------------- GEMM v2p: C[M][N] = A[M][K] @ Bt[N][K]^T (bf16 in) ----------------
// ROUND-6 VERIFIED VERSION RESTORED (66.8 us QKV). 128x128 tile, BK=32, double-
// buffered LDS (32 KiB), 2-phase __syncthreads pipeline, XOR chunk swizzle, 3
// blocks/CU. Round-7 lesson: B frags direct-from-global thrash L2 (12 MB/XCD
// working set) -> 2x regression; B stays in LDS.
template <int BF16_OUT>
__global__ __launch_bounds__(256, 3) void gemm_bt2p(const short* __restrict__ A,
                                                    const short* __restrict__ Bt,
                                                    void* __restrict__ Cout,
                                                    const float* __restrict__ bias,
                                                    int N, int K, int nbx, int cpx) {
  __shared__ __align__(16) short sm[2 * 8192];  // 2 bufs x (A[128][32] | B[128][32])
  const int tid = threadIdx.x;
  const int w = tid >> 6, lane = tid & 63, quad = lane >> 4, l16 = lane & 15;
  const int wm = (w >> 1) * 64, wn = (w & 1) * 64;
  const int bid = blockIdx.x;
  const int swz = (bid & 7) * cpx + (bid >> 3);
  const int n0 = (swz % nbx) * 128, m0 = (swz / nbx) * 128;
  const int NT = K >> 5;

  const int srow = lane >> 2;
  const int sc = ((lane & 3) ^ ((lane >> 2) & 3) ^ ((lane >> 4) & 3)) * 8;
  const short* Ag = A + (size_t)(m0 + w * 16 + srow) * K + sc;
  const short* Bg = Bt + (size_t)(n0 + w * 16 + srow) * K + sc;
  short* Ad = sm + w * 512 + lane * 8;
  short* Bd = sm + 4096 + w * 512 + lane * 8;
  const size_t rjump = (size_t)64 * K;

  auto stage = [&](int t, int bf_) {
    const int k = t << 5;
    short* ad = Ad + bf_ * 8192;
    short* bd = Bd + bf_ * 8192;
    gll16(Ag + k, ad);
    gll16(Ag + k + rjump, ad + 2048);
    gll16(Bg + k, bd);
    gll16(Bg + k + rjump, bd + 2048);
  };

  const int rsc = (quad ^ (l16 & 3) ^ ((l16 >> 2) & 3)) * 8;
  const short* aBase = sm + (wm + l16) * 32 + rsc;
  const short* bBase = sm + 4096 + (wn + l16) * 32 + rsc;

  v4f acc[4][4] = {};

  stage(0, 0);
  __syncthreads();

  for (int t = 0; t < NT; ++t) {
    if (t + 1 < NT) stage(t + 1, (t + 1) & 1);  // overlaps with this tile's compute
    const int bo_ = (t & 1) * 8192;
    v8s af[4], bf[4];
#pragma unroll
    for (int i = 0; i < 4; ++i) af[i] = *(const v8s*)(aBase + bo_ + i * 512);
#pragma unroll
    for (int i = 0; i < 4; ++i) bf[i] = *(const v8s*)(bBase + bo_ + i * 512);
    __builtin_amdgcn_s_setprio(1);
#pragma unroll
    for (int mi = 0; mi < 4; ++mi)
#pragma unroll
      for (int ni = 0; ni < 4; ++ni)
        acc[mi][ni] = __builtin_amdgcn_mfma_f32_16x16x32_bf16(af[mi], bf[ni], acc[mi][ni], 0, 0, 0);
    __builtin_amdgcn_s_setprio(0);
    if (t + 1 < NT) __syncthreads();  // drains stage(t+1); publishes buf (t+1)&1
  }

#pragma unroll
  for (int mi = 0; mi < 4; ++mi) {
#pragma unroll
    for (int ni = 0; ni < 4; ++ni) {
      const int col = n0 + wn + ni * 16 + l16;
#pragma unroll
      for (int r = 0; r < 4; ++r) {
        const int row = m0 + wm + mi * 16 + quad * 4 + r;
        if (BF16_OUT) {
          ((short*)Cout)[(size_t)row * N + col] = f2bf(acc[mi][ni][r]);
        } else {
          ((float*)Cout)[(size_t)row * N + col] = acc[mi][ni][r] + bias[col];
        }
      }
    }
  }
}

// ---------------- flash attention v8 ----------------
// LDS-read-bound fix: qs=2 per wave (v5's verified compute loop) at 8 waves
// (v7's verified staging): wq in 0..3 owns 32 q-rows, wk in 0..1 owns 32 keys.
// T=128-row q-tiles, grid (8,32)=256 blocks (pair qt & 15-qt -> uniform 34 ktiles),
// 1 blk/CU, 2 waves/SIMD. Same 16 ds_read_b128/wave/ktile now feed 34 MFMAs (was
// 17) -> LDS bytes/FLOP halves (total reads 2.16 -> 1.11 GB).
__global__ __launch_bounds__(512, 2) void flash_attn8(const short* __restrict__ QKV,
                                                      const short* __restrict__ Vtb,
                                                      short* __restrict__ ctx) {
  __shared__ __align__(16) short smem[32768];  // 2 x (Ks 8192 + Vs 8192); epilogue overlay
  const int tid = threadIdx.x;
  const int w = tid >> 6, lane = tid & 63, quad = lane >> 4, l16 = lane & 15;
  const int wq = w >> 1, wk = w & 1;                 // wq in 0..3
  const int bh = blockIdx.y;
  const int b = bh >> 4, h = bh & 15, g = h >> 2;
  v8s ones;
#pragma unroll
  for (int i = 0; i < 8; ++i) ones[i] = (short)0x3F80;

  // staging lane roles (v7 verbatim): wave w stages K rows w*8..+7, V d-rows w*16..+15
  const int krl = lane >> 4, kcl = lane & 15;
  const int vrl = lane >> 3, vcl = lane & 7;
  const short* Kg0 = QKV + (size_t)(b * 2048 + w * 8 + krl) * 3072 + 2048 + g * 128;
  const short* Vg0 = Vtb + (size_t)(b * 512 + g * 128 + w * 16 + vrl) * 2048 + (vcl ^ (vrl & 7)) * 8;
  short* kd = smem + (w * 8) * 128 + lane * 8;
  short* vd = smem + 8192 + (w * 16) * 64 + lane * 8;

  auto stage = [&](int key0, int bs) {
    const short* kg = Kg0 + (size_t)key0 * 3072;
    const short* vg = Vg0 + key0;
#pragma unroll
    for (int ii = 0; ii < 2; ++ii) {
      const int rl = (w & 1) * 8 + ii * 4 + krl;   // = (staged K row) & 15
      gll16(kg + (size_t)(ii * 4) * 3072 + (kcl ^ rl) * 8, kd + bs * 16384 + ii * 512);
      gll16(vg + (size_t)(ii * 8) * 2048, vd + bs * 16384 + ii * 512);
    }
  };

  float* red = (float*)smem;

#pragma unroll 1
  for (int half = 0; half < 2; ++half) {
    const int qt = half ? (15 - blockIdx.x) : blockIdx.x;
    const int q0 = qt * 128;
    const int qb = q0 + wq * 32;

    // Q fragments: 2 qsets of 16 rows (MFMA B-operand for S^T = K*Q^T)  [v5 verbatim]
    v8s aq[2][4];
#pragma unroll
    for (int qs = 0; qs < 2; ++qs) {
      const short* Qp = QKV + (size_t)(b * 2048 + qb + qs * 16 + l16) * 3072 + h * 128 + quad * 8;
#pragma unroll
      for (int kk = 0; kk < 4; ++kk) aq[qs][kk] = *(const v8s*)(Qp + kk * 32);
    }
    v4f o[2][8] = {};
    v4f ol[2] = {};

    __syncthreads();            // protect smem from previous half's epilogue readers
    stage(0, 0);
    const int nk = 2 * qt + 2;
#pragma unroll 1
    for (int kt = 0; kt < nk; ++kt) {
      const int key0 = kt << 6;
      __syncthreads();          // drains stage(kt) [vmcnt(0)], orders buffer reuse
      if (kt + 1 < nk) stage((kt + 1) << 6, (kt + 1) & 1);
      const short* Ks = smem + (kt & 1) * 16384;
      const short* Vs = Ks + 8192;
      const int kb = key0 + wk * 32;
      if (kb > qb + 31) continue;  // wave-uniform: fully masked
      // S^T = K @ Q^T for this wave's 32 keys x 32 q  [v5 verbatim]
      v4f sf[2][2] = {};
      __builtin_amdgcn_s_setprio(1);
#pragma unroll
      for (int kfl = 0; kfl < 2; ++kfl)
#pragma unroll
        for (int kk = 0; kk < 4; ++kk) {
          v8s kfr = *(const v8s*)&Ks[((wk * 2 + kfl) * 16 + l16) * 128 + (((kk * 4 + quad) ^ l16) * 8)];
#pragma unroll
          for (int qs = 0; qs < 2; ++qs)
            sf[qs][kfl] = __builtin_amdgcn_mfma_f32_16x16x32_bf16(kfr, aq[qs][kk], sf[qs][kfl], 0, 0, 0);
        }
      __builtin_amdgcn_s_setprio(0);
      // mask + exp2 + cvt_pk pack -> PV A-frag (32 keys)
      const bool diag = (kb + 31 > qb);
      v8s pa[2];
#pragma unroll
      for (int qs = 0; qs < 2; ++qs) {
        const int qg = qb + qs * 16 + l16;
        union { v8s v; unsigned u[4]; } pu;
#pragma unroll
        for (int kfl = 0; kfl < 2; ++kfl) {
          float e[4];
#pragma unroll
          for (int r = 0; r < 4; ++r) {
            float s = sf[qs][kfl][r];
            if (diag && (kb + kfl * 16 + quad * 4 + r > qg)) s = -1e30f;
            e[r] = exp2f(s);
          }
          asm("v_cvt_pk_bf16_f32 %0, %1, %2" : "=v"(pu.u[kfl * 2 + 0]) : "v"(e[0]), "v"(e[1]));
          asm("v_cvt_pk_bf16_f32 %0, %1, %2" : "=v"(pu.u[kfl * 2 + 1]) : "v"(e[2]), "v"(e[3]));
        }
        pa[qs] = pu.v;
      }
      // O += P @ V ; l += P @ 1  [v5 verbatim]
      __builtin_amdgcn_s_setprio(1);
#pragma unroll
      for (int nf = 0; nf < 8; ++nf) {
        v8s vf = *(const v8s*)&Vs[(nf * 16 + l16) * 64 + (((wk * 4 + quad) ^ (l16 & 7)) * 8)];
#pragma unroll
        for (int qs = 0; qs < 2; ++qs)
          o[qs][nf] = __builtin_amdgcn_mfma_f32_16x16x32_bf16(pa[qs], vf, o[qs][nf], 0, 0, 0);
      }
#pragma unroll
      for (int qs = 0; qs < 2; ++qs)
        ol[qs] = __builtin_amdgcn_mfma_f32_16x16x32_bf16(pa[qs], ones, ol[qs], 0, 0, 0);
      __builtin_amdgcn_s_setprio(0);
    }
    __syncthreads();   // all LDS reads of K/V done; smem becomes reduction buffer

    // ---- epilogue: sum o/l across the wk pair, normalize, store ----
    // phase A: l   (wq in 0..3: max idx 7*256+255 = 2047 floats, fits)
    if (wk == 1) {
#pragma unroll
      for (int qs = 0; qs < 2; ++qs)
        *(v4f*)&red[(wq * 2 + qs) * 256 + l16 * 16 + quad * 4] = ol[qs];
    }
    __syncthreads();
    if (wk == 0) {
#pragma unroll
      for (int qs = 0; qs < 2; ++qs)
        ol[qs] += *(const v4f*)&red[(wq * 2 + qs) * 256 + l16 * 16 + quad * 4];
    }
    __syncthreads();
    // phase B: o   (max idx ((7*8+7)*256)+255 = 16383 floats = 64 KiB, fits exactly)
    if (wk == 1) {
#pragma unroll
      for (int qs = 0; qs < 2; ++qs)
#pragma unroll
        for (int nf = 0; nf < 8; ++nf)
          *(v4f*)&red[(((wq * 2 + qs) * 8 + nf) * 256) + l16 * 16 + quad * 4] = o[qs][nf];
    }
    __syncthreads();
    if (wk == 0) {
#pragma unroll
      for (int qs = 0; qs < 2; ++qs) {
        float inv[4];
#pragma unroll
        for (int r = 0; r < 4; ++r) inv[r] = 1.0f / ol[qs][r];
#pragma unroll
        for (int nf = 0; nf < 8; ++nf) {
          v4f osum = o[qs][nf] + *(const v4f*)&red[(((wq * 2 + qs) * 8 + nf) * 256) + l16 * 16 + quad * 4];
#pragma unroll
          for (int r = 0; r < 4; ++r) {
            const int row = qb + qs * 16 + quad * 4 + r;
            ctx[(size_t)(b * 2048 + row) * 2048 + h * 128 + nf * 16 + l16] = f2bf(osum[r] * inv[r]);
          }
        }
      }
    }
  }
}

extern "C" void kernel_launch(void* const* d_in, const int* in_sizes, int n_in,
                              void* d_out, int out_size, void* d_ws, size_t ws_size,
                              hipStream_t stream) {
  const float* x = (const float*)d_in[0];
  const float* Wq = (const float*)d_in[1];
  const float* Wk = (const float*)d_in[2];
  const float* Wv = (const float*)d_in[3];
  const float* Wo = (const float*)d_in[4];
  const float* bo = (const float*)d_in[5];
  float* out = (float*)d_out;
  char* ws = (char*)d_ws;

  // workspace layout (bytes), total 64 MiB; ctx aliases xb
  short* xb    = (short*)(ws);             // 16,777,216  x bf16 [4096][2048]
  short* ctx   = (short*)(ws);             // alias       [4096][2048]
  short* Wqkvt = (short*)(ws + 16777216);  // 12,582,912  [3072 n][2048 k] packed Q|K|V
  short* Wot   = (short*)(ws + 29360128);  //  8,388,608  [2048 n][2048 k]
  short* QKV   = (short*)(ws + 37748736);  // 25,165,824  [4096][3072]
  short* Vtb   = (short*)(ws + 62914560);  //  4,194,304  [b][512][2048] key-permuted

  cast_and_transpose<<<18432, 256, 0, stream>>>(x, xb, Wq, Wk, Wv, Wo, Wqkvt, Wot);

  // QKV: M=4096,N=3072,K=2048 -> 24x32=768 blocks = exactly 3/CU
  gemm_bt2p<1><<<768, 256, 0, stream>>>(xb, Wqkvt, (void*)QKV, nullptr, 3072, 2048, 24, 96);

  transpose_v_perm<<<dim3(16, 64, 2), dim3(32, 8), 0, stream>>>(QKV, Vtb);

  flash_attn8<<<dim3(8, 32), 512, 0, stream>>>(QKV, Vtb, ctx);

  // out: M=4096,N=2048,K=2048 -> 16x32=512 blocks = 2/CU
  gemm_bt2p<0><<<512, 256, 0, stream>>>(ctx, Wot, (void*)out, bo, 2048, 2048, 16, 64);
}